// Round 8
// baseline (935.164 us; speedup 1.0000x reference)
//
#include <hip/hip_runtime.h>
#include <hip/hip_fp16.h>
#include <cstddef>
#include <cstdint>

#define N_NODES   100000
#define N_EDGES   1600000
#define N_GRAPHS  512
#define HIDDEN    128
#define N_LAYERS  3

#define SCAN_BS   1024
#define SCAN_NB   ((N_NODES + SCAN_BS - 1) / SCAN_BS)   // 98

// 8 dst-range slots, 12500 nodes each
#define NPX        (N_NODES / 8)
#define BIN_BLOCKS 512
#define BIN_CHUNK  (N_EDGES / BIN_BLOCKS)   // 3125 exactly
#define DS_STRIPES 64

// windowed counting-sort scatter: line ownership is structural (each window
// block owns a contiguous csr range) -- no XCD-mapping assumption needed
#define WIN_NODES     500
#define WINS_PER_SLOT (NPX / WIN_NODES)     // 25

typedef _Float16 half8 __attribute__((ext_vector_type(8)));
typedef float    float8 __attribute__((ext_vector_type(8)));
typedef float    floatx4 __attribute__((ext_vector_type(4)));

// ---------------------------------------------------------------------------
// Edge bucketing by dst-slot (deterministic, packed int2{dst,src}).
// ---------------------------------------------------------------------------
__global__ __launch_bounds__(256) void bin_count_kernel(const int* __restrict__ dst,
                                                        int* __restrict__ counts) {
    const int e0 = blockIdx.x * BIN_CHUNK, e1 = e0 + BIN_CHUNK;
    int c0=0,c1=0,c2=0,c3=0,c4=0,c5=0,c6=0,c7=0;
    for (int e = e0 + threadIdx.x; e < e1; e += 256) {
        int s = dst[e] / NPX;
        c0 += (s==0); c1 += (s==1); c2 += (s==2); c3 += (s==3);
        c4 += (s==4); c5 += (s==5); c6 += (s==6); c7 += (s==7);
    }
    __shared__ int cs[8];
    if (threadIdx.x < 8) cs[threadIdx.x] = 0;
    __syncthreads();
    atomicAdd(&cs[0], c0); atomicAdd(&cs[1], c1);
    atomicAdd(&cs[2], c2); atomicAdd(&cs[3], c3);
    atomicAdd(&cs[4], c4); atomicAdd(&cs[5], c5);
    atomicAdd(&cs[6], c6); atomicAdd(&cs[7], c7);
    __syncthreads();
    if (threadIdx.x < 8) counts[blockIdx.x * 8 + threadIdx.x] = cs[threadIdx.x];
}

__global__ __launch_bounds__(512) void bin_scan_kernel(const int* __restrict__ counts,
                                                       int* __restrict__ offsets,
                                                       int* __restrict__ slotbase) {
    __shared__ int tmp[512];
    __shared__ int totpost;
    const int t = threadIdx.x;
    int base = 0;
    for (int s = 0; s < 8; ++s) {
        tmp[t] = counts[t * 8 + s];
        __syncthreads();
        for (int off = 1; off < 512; off <<= 1) {
            int u = (t >= off) ? tmp[t - off] : 0;
            __syncthreads();
            tmp[t] += u;
            __syncthreads();
        }
        int excl = (t == 0) ? 0 : tmp[t - 1];
        offsets[t * 8 + s] = base + excl;
        if (t == 511) totpost = tmp[511];
        if (t == 0) slotbase[s] = base;
        __syncthreads();
        base += totpost;
        __syncthreads();
    }
    if (t == 0) slotbase[8] = base;   // == N_EDGES
}

__global__ __launch_bounds__(256) void bin_place_kernel(const int* __restrict__ src,
                                                        const int* __restrict__ dst,
                                                        const int* __restrict__ offsets,
                                                        int2* __restrict__ bedge) {
    __shared__ int off[8];
    if (threadIdx.x < 8) off[threadIdx.x] = offsets[blockIdx.x * 8 + threadIdx.x];
    __syncthreads();
    const int e0 = blockIdx.x * BIN_CHUNK, e1 = e0 + BIN_CHUNK;
    for (int e = e0 + threadIdx.x; e < e1; e += 256) {
        int d = dst[e];
        int s = d / NPX;
        int p = atomicAdd(&off[s], 1);
        bedge[p] = make_int2(d, src[e]);
    }
}

// ---------------------------------------------------------------------------
__global__ __launch_bounds__(256) void deg_kernel(const int2* __restrict__ bedge,
                                                  const int* __restrict__ slotbase,
                                                  int* __restrict__ deg) {
    const int s = blockIdx.x & 7, stripe = blockIdx.x >> 3;
    const int b0 = slotbase[s], b1 = slotbase[s + 1];
    const int cnt = b1 - b0;
    const int per = (cnt + DS_STRIPES - 1) / DS_STRIPES;
    const int e0 = b0 + stripe * per;
    int e1 = e0 + per; if (e1 > b1) e1 = b1;
    for (int e = e0 + threadIdx.x; e < e1; e += 256)
        atomicAdd(&deg[bedge[e].x], 1);
}

// windowed counting sort: block = (slot, window of 500 nodes). LDS running
// positions; csr writes land in this block's contiguous ~32KB range only.
__global__ __launch_bounds__(256) void scatter_kernel(const int2* __restrict__ bedge,
                                                      const int* __restrict__ slotbase,
                                                      const int* __restrict__ posb,
                                                      int* __restrict__ csr_src) {
    __shared__ int wpos[WIN_NODES];
    const int s   = blockIdx.x & 7;
    const int win = blockIdx.x >> 3;
    const int w0  = s * NPX + win * WIN_NODES;
    for (int i = threadIdx.x; i < WIN_NODES; i += 256) wpos[i] = posb[w0 + i];
    __syncthreads();
    const int b0 = slotbase[s], b1 = slotbase[s + 1];
    for (int e = b0 + threadIdx.x; e < b1; e += 256) {
        int2 ed = bedge[e];
        unsigned r = (unsigned)(ed.x - w0);
        if (r < WIN_NODES) {
            int p = atomicAdd(&wpos[r], 1);
            csr_src[p] = ed.y;
        }
    }
}

// ---------------------------------------------------------------------------
// node-degree hierarchical scan (R2-confirmed)
// ---------------------------------------------------------------------------
__global__ __launch_bounds__(SCAN_BS) void scan_blocks_kernel(const int* __restrict__ deg,
                                                              int* __restrict__ scanned,
                                                              int* __restrict__ bsums) {
    __shared__ int tmp[SCAN_BS];
    const int t = threadIdx.x;
    const int i = blockIdx.x * SCAN_BS + t;
    int v = (i < N_NODES) ? deg[i] : 0;
    tmp[t] = v;
    __syncthreads();
#pragma unroll
    for (int off = 1; off < SCAN_BS; off <<= 1) {
        int u = (t >= off) ? tmp[t - off] : 0;
        __syncthreads();
        tmp[t] += u;
        __syncthreads();
    }
    if (i < N_NODES) scanned[i] = tmp[t];
    if (t == SCAN_BS - 1) bsums[blockIdx.x] = tmp[t];
}

__global__ __launch_bounds__(128) void scan_tops_kernel(int* __restrict__ bsums) {
    __shared__ int tmp[128];
    const int t = threadIdx.x;
    tmp[t] = (t < SCAN_NB) ? bsums[t] : 0;
    __syncthreads();
#pragma unroll
    for (int off = 1; off < 128; off <<= 1) {
        int u = (t >= off) ? tmp[t - off] : 0;
        __syncthreads();
        tmp[t] += u;
        __syncthreads();
    }
    if (t < SCAN_NB) bsums[t] = tmp[t];
}

__global__ __launch_bounds__(SCAN_BS) void scan_finalize_kernel(const int* __restrict__ deg,
                                                                const int* __restrict__ scanned,
                                                                const int* __restrict__ bsums,
                                                                int* __restrict__ row_ptr,
                                                                int* __restrict__ posb) {
    const int b = blockIdx.x;
    const int i = b * SCAN_BS + threadIdx.x;
    if (i >= N_NODES) return;
    const int off = (b > 0) ? bsums[b - 1] : 0;
    const int inc = off + scanned[i];
    row_ptr[i + 1] = inc;
    posb[i] = inc - deg[i];
    if (i == 0) row_ptr[0] = 0;
}

// ---------------------------------------------------------------------------
__global__ void f2h_kernel(const float* __restrict__ in, __half* __restrict__ out) {
    int t = blockIdx.x * blockDim.x + threadIdx.x;
    const int n8 = (N_NODES * HIDDEN) / 8;
    if (t >= n8) return;
    const float4* in4 = (const float4*)in;
    float4 a = in4[t * 2 + 0];
    float4 b = in4[t * 2 + 1];
    __half2* o2 = (__half2*)out;
    o2[t * 4 + 0] = __floats2half2_rn(a.x, a.y);
    o2[t * 4 + 1] = __floats2half2_rn(a.z, a.w);
    o2[t * 4 + 2] = __floats2half2_rn(b.x, b.y);
    o2[t * 4 + 3] = __floats2half2_rn(b.z, b.w);
}

__global__ void wconv_kernel(const float* __restrict__ w1, const float* __restrict__ w2,
                             __half* __restrict__ wt1, __half* __restrict__ wt2) {
    int t = blockIdx.x * blockDim.x + threadIdx.x;
    if (t >= N_LAYERS * HIDDEN * HIDDEN) return;
    int l = t / (HIDDEN * HIDDEN);
    int r = t - l * (HIDDEN * HIDDEN);
    int k = r / HIDDEN, n = r - k * HIDDEN;
    wt1[(size_t)l * HIDDEN * HIDDEN + n * HIDDEN + k] = __float2half(w1[t]);
    wt2[(size_t)l * HIDDEN * HIDDEN + n * HIDDEN + k] = __float2half(w2[t]);
}

// ---------------------------------------------------------------------------
// GIN aggregation (R7-confirmed): half8 loads, 4 rows per wave-load,
// shfl butterfly reduce, fp32 accumulate.
// ---------------------------------------------------------------------------
__global__ void gather_kernel(const __half* __restrict__ Xh, __half* __restrict__ Zh,
                              const int* __restrict__ row_ptr,
                              const int* __restrict__ csr_src) {
    int wave = (blockIdx.x * blockDim.x + threadIdx.x) >> 6;
    int lane = threadIdx.x & 63;
    if (wave >= N_NODES) return;
    const int grp = lane >> 4;
    const int m   = lane & 15;
    const half8* H8 = (const half8*)Xh;

    float8 acc = {0.f,0.f,0.f,0.f,0.f,0.f,0.f,0.f};
    int k = row_ptr[wave];
    const int end = row_ptr[wave + 1];

    for (; k + 8 <= end; k += 8) {
        int n0 = csr_src[k + grp];
        int n1 = csr_src[k + 4 + grp];
        half8 v0 = H8[(size_t)n0 * 16 + m];
        half8 v1 = H8[(size_t)n1 * 16 + m];
        acc += __builtin_convertvector(v0, float8);
        acc += __builtin_convertvector(v1, float8);
    }
    if (k + 4 <= end) {
        int n0 = csr_src[k + grp];
        half8 v0 = H8[(size_t)n0 * 16 + m];
        acc += __builtin_convertvector(v0, float8);
        k += 4;
    }
    int rem = end - k;
    if (grp < rem) {
        int n0 = csr_src[k + grp];
        half8 v0 = H8[(size_t)n0 * 16 + m];
        acc += __builtin_convertvector(v0, float8);
    }

#pragma unroll
    for (int j = 0; j < 8; ++j) acc[j] += __shfl_xor(acc[j], 16);
#pragma unroll
    for (int j = 0; j < 8; ++j) acc[j] += __shfl_xor(acc[j], 32);

    half8 sv = H8[(size_t)wave * 16 + m];
    acc += __builtin_convertvector(sv, float8);

    if (grp == 0) {
        half8 o = __builtin_convertvector(acc, half8);
        ((half8*)Zh)[(size_t)wave * 16 + m] = o;
    }
}

// ---------------------------------------------------------------------------
// MFMA GEMM (R6-verified layouts): C = relu(A @ W + bias), fp16 io/fp32 acc.
// ---------------------------------------------------------------------------
__global__ __launch_bounds__(256) void mm16_kernel(const __half* __restrict__ A,
                                                   const __half* __restrict__ Wt,
                                                   const float* __restrict__ bias,
                                                   __half* __restrict__ C16, int M) {
    const int wave = threadIdx.x >> 6;
    const int lane = threadIdx.x & 63;
    const int m = lane & 15;
    const int q = lane >> 4;
    const int row0 = blockIdx.x * 64 + wave * 16;

    int ra = row0 + m; if (ra > M - 1) ra = M - 1;
    const half8* Arow = (const half8*)(A + (size_t)ra * HIDDEN);
    half8 a0 = Arow[q];
    half8 a1 = Arow[4 + q];
    half8 a2 = Arow[8 + q];
    half8 a3 = Arow[12 + q];

#pragma unroll
    for (int ct = 0; ct < 8; ++ct) {
        const int n = ct * 16 + m;
        const half8* Wrow = (const half8*)(Wt + (size_t)n * HIDDEN);
        floatx4 acc = {0.f, 0.f, 0.f, 0.f};
        acc = __builtin_amdgcn_mfma_f32_16x16x32_f16(a0, Wrow[q],      acc, 0, 0, 0);
        acc = __builtin_amdgcn_mfma_f32_16x16x32_f16(a1, Wrow[4 + q],  acc, 0, 0, 0);
        acc = __builtin_amdgcn_mfma_f32_16x16x32_f16(a2, Wrow[8 + q],  acc, 0, 0, 0);
        acc = __builtin_amdgcn_mfma_f32_16x16x32_f16(a3, Wrow[12 + q], acc, 0, 0, 0);
        const float b = bias[n];
#pragma unroll
        for (int r = 0; r < 4; ++r) {
            int row = row0 + q * 4 + r;
            if (row < M) {
                float v = fmaxf(acc[r] + b, 0.f);
                C16[(size_t)row * HIDDEN + n] = __float2half(v);
            }
        }
    }
}

// ---------------------------------------------------------------------------
#define POOL_CHUNK 128
__global__ void pool_kernel(const __half* __restrict__ Xh, const int* __restrict__ batch,
                            float* __restrict__ pooled, int layer) {
    const int f = threadIdx.x;
    int start = blockIdx.x * POOL_CHUNK;
    int end = start + POOL_CHUNK;
    if (end > N_NODES) end = N_NODES;
    float acc = 0.f;
    int gcur = batch[start];
    for (int n = start; n < end; ++n) {
        int g = batch[n];
        if (g != gcur) {
            atomicAdd(&pooled[(size_t)gcur * (HIDDEN * N_LAYERS) + layer * HIDDEN + f], acc);
            acc = 0.f;
            gcur = g;
        }
        acc += __half2float(Xh[(size_t)n * HIDDEN + f]);
    }
    atomicAdd(&pooled[(size_t)gcur * (HIDDEN * N_LAYERS) + layer * HIDDEN + f], acc);
}

// ---------------------------------------------------------------------------
__global__ __launch_bounds__(128) void cls_kernel(const float* __restrict__ pooled,
                                                  const float* __restrict__ w1,
                                                  const float* __restrict__ b1,
                                                  const float* __restrict__ w2,
                                                  const float* __restrict__ b2,
                                                  const float* __restrict__ w3,
                                                  const float* __restrict__ b3,
                                                  float* __restrict__ out) {
    __shared__ float hin[HIDDEN * N_LAYERS];
    __shared__ float h1[HIDDEN];
    __shared__ float red[HIDDEN];
    const int g = blockIdx.x;
    const int t = threadIdx.x;

    for (int i = t; i < HIDDEN * N_LAYERS; i += 128)
        hin[i] = pooled[(size_t)g * (HIDDEN * N_LAYERS) + i];
    __syncthreads();

    float s = 0.f;
    for (int k = 0; k < HIDDEN * N_LAYERS; ++k) s += hin[k] * w1[(size_t)k * HIDDEN + t];
    s = fmaxf(s + b1[t], 0.f);
    h1[t] = s;
    __syncthreads();

    float s2 = 0.f;
    for (int k = 0; k < HIDDEN; ++k) s2 += h1[k] * w2[(size_t)k * HIDDEN + t];
    s2 = fmaxf(s2 + b2[t], 0.f);

    red[t] = s2 * w3[t];
    __syncthreads();
    for (int off = 64; off > 0; off >>= 1) {
        if (t < off) red[t] += red[t + off];
        __syncthreads();
    }
    if (t == 0) out[g] = red[0] + b3[0];
}

// ---------------------------------------------------------------------------
extern "C" void kernel_launch(void* const* d_in, const int* in_sizes, int n_in,
                              void* d_out, int out_size, void* d_ws, size_t ws_size,
                              hipStream_t stream) {
    const float* X     = (const float*)d_in[0];
    const int*   ei    = (const int*)d_in[1];
    const int*   batch = (const int*)d_in[2];
    const float* w1all = (const float*)d_in[3];
    const float* b1all = (const float*)d_in[4];
    const float* w2all = (const float*)d_in[5];
    const float* b2all = (const float*)d_in[6];
    const float* cw1   = (const float*)d_in[7];
    const float* cb1   = (const float*)d_in[8];
    const float* cw2   = (const float*)d_in[9];
    const float* cb2   = (const float*)d_in[10];
    const float* cw3   = (const float*)d_in[11];
    const float* cb3   = (const float*)d_in[12];
    float* out = (float*)d_out;

    const int* src = ei;
    const int* dst = ei + N_EDGES;

    char* p = (char*)d_ws;
    auto alloc = [&](size_t bytes) {
        char* r = p;
        p += (bytes + 255) & ~(size_t)255;
        return r;
    };
    __half* hA      = (__half*)alloc((size_t)N_NODES * HIDDEN * sizeof(__half));
    __half* hB      = (__half*)alloc((size_t)N_NODES * HIDDEN * sizeof(__half));
    __half* zh      = (__half*)alloc((size_t)N_NODES * HIDDEN * sizeof(__half));
    __half* m1h     = (__half*)alloc((size_t)N_NODES * HIDDEN * sizeof(__half));
    __half* wt1     = (__half*)alloc((size_t)N_LAYERS * HIDDEN * HIDDEN * sizeof(__half));
    __half* wt2     = (__half*)alloc((size_t)N_LAYERS * HIDDEN * HIDDEN * sizeof(__half));
    int2*   bedge   = (int2*)alloc((size_t)N_EDGES * sizeof(int2));
    int*    csr     = (int*)alloc((size_t)N_EDGES * sizeof(int));
    int*    rowp    = (int*)alloc((size_t)(N_NODES + 1) * sizeof(int));
    int*    posb    = (int*)alloc((size_t)N_NODES * sizeof(int));
    int*    deg     = (int*)alloc((size_t)N_NODES * sizeof(int));
    int*    scanned = (int*)alloc((size_t)N_NODES * sizeof(int));
    int*    bsums   = (int*)alloc((size_t)SCAN_NB * sizeof(int));
    int*    counts  = (int*)alloc((size_t)BIN_BLOCKS * 8 * sizeof(int));
    int*    offsets = (int*)alloc((size_t)BIN_BLOCKS * 8 * sizeof(int));
    int*    slotbase= (int*)alloc(9 * sizeof(int));
    float*  pooled  = (float*)alloc((size_t)N_GRAPHS * HIDDEN * N_LAYERS * sizeof(float));

    hipMemsetAsync(deg, 0, (size_t)N_NODES * sizeof(int), stream);
    hipMemsetAsync(pooled, 0, (size_t)N_GRAPHS * HIDDEN * N_LAYERS * sizeof(float), stream);

    bin_count_kernel<<<BIN_BLOCKS, 256, 0, stream>>>(dst, counts);
    bin_scan_kernel<<<1, 512, 0, stream>>>(counts, offsets, slotbase);
    bin_place_kernel<<<BIN_BLOCKS, 256, 0, stream>>>(src, dst, offsets, bedge);
    deg_kernel<<<8 * DS_STRIPES, 256, 0, stream>>>(bedge, slotbase, deg);
    scan_blocks_kernel<<<SCAN_NB, SCAN_BS, 0, stream>>>(deg, scanned, bsums);
    scan_tops_kernel<<<1, 128, 0, stream>>>(bsums);
    scan_finalize_kernel<<<SCAN_NB, SCAN_BS, 0, stream>>>(deg, scanned, bsums, rowp, posb);
    scatter_kernel<<<8 * WINS_PER_SLOT, 256, 0, stream>>>(bedge, slotbase, posb, csr);

    const int f2h_grid = ((N_NODES * HIDDEN / 8) + 255) / 256;
    f2h_kernel<<<f2h_grid, 256, 0, stream>>>(X, hA);
    wconv_kernel<<<(N_LAYERS * HIDDEN * HIDDEN + 255) / 256, 256, 0, stream>>>(w1all, w2all, wt1, wt2);

    const int mm_grid   = (N_NODES + 63) / 64;
    const int gat_grid  = (N_NODES + 3) / 4;
    const int pool_grid = (N_NODES + POOL_CHUNK - 1) / POOL_CHUNK;

    __half* hcur = hA;
    for (int l = 0; l < N_LAYERS; ++l) {
        __half* hnext = (l & 1) ? hA : hB;
        gather_kernel<<<gat_grid, 256, 0, stream>>>(hcur, zh, rowp, csr);
        mm16_kernel<<<mm_grid, 256, 0, stream>>>(zh,
                                                 wt1 + (size_t)l * HIDDEN * HIDDEN,
                                                 b1all + (size_t)l * HIDDEN,
                                                 m1h, N_NODES);
        mm16_kernel<<<mm_grid, 256, 0, stream>>>(m1h,
                                                 wt2 + (size_t)l * HIDDEN * HIDDEN,
                                                 b2all + (size_t)l * HIDDEN,
                                                 hnext, N_NODES);
        pool_kernel<<<pool_grid, POOL_CHUNK, 0, stream>>>(hnext, batch, pooled, l);
        hcur = hnext;
    }

    cls_kernel<<<N_GRAPHS, 128, 0, stream>>>(pooled, cw1, cb1, cw2, cb2, cw3, cb3, out);
}

// Round 9
// 704.802 us; speedup vs baseline: 1.3268x; 1.3268x over previous
//
#include <hip/hip_runtime.h>
#include <hip/hip_fp16.h>
#include <cstddef>
#include <cstdint>

#define N_NODES   100000
#define N_EDGES   1600000
#define N_GRAPHS  512
#define HIDDEN    128
#define N_LAYERS  3

#define SCAN_BS   1024
#define SCAN_NB   ((N_NODES + SCAN_BS - 1) / SCAN_BS)   // 98

// 400-way counting sort: windows of 250 dst-nodes. Each downstream block
// streams ONLY its own window bucket (R8 lesson: no re-read), and csr-line
// ownership stays structural (R8-verified: write amp eliminated).
#define N_WIN      400
#define WIN_NODES  (N_NODES / N_WIN)        // 250
#define BIN_BLOCKS 512
#define BIN_CHUNK  (N_EDGES / BIN_BLOCKS)   // 3125 exactly

typedef _Float16 half8 __attribute__((ext_vector_type(8)));
typedef float    float8 __attribute__((ext_vector_type(8)));
typedef float    floatx4 __attribute__((ext_vector_type(4)));

// ---------------------------------------------------------------------------
// 1) per-block 400-bin histogram of dst windows
// ---------------------------------------------------------------------------
__global__ __launch_bounds__(256) void win_count_kernel(const int* __restrict__ dst,
                                                        int* __restrict__ counts) {
    __shared__ int cs[N_WIN];
    for (int i = threadIdx.x; i < N_WIN; i += 256) cs[i] = 0;
    __syncthreads();
    const int e0 = blockIdx.x * BIN_CHUNK, e1 = e0 + BIN_CHUNK;
    for (int e = e0 + threadIdx.x; e < e1; e += 256)
        atomicAdd(&cs[dst[e] / WIN_NODES], 1);
    __syncthreads();
    for (int i = threadIdx.x; i < N_WIN; i += 256)
        counts[blockIdx.x * N_WIN + i] = cs[i];
}

// 2a) column scan: offsets[b][w] = prefix_b(counts[.][w]); colsum[w] = total
__global__ __launch_bounds__(512) void win_scan1_kernel(const int* __restrict__ counts,
                                                        int* __restrict__ offsets,
                                                        int* __restrict__ colsum) {
    __shared__ int tmp[512];
    const int w = blockIdx.x;
    const int t = threadIdx.x;
    tmp[t] = counts[t * N_WIN + w];
    __syncthreads();
#pragma unroll
    for (int off = 1; off < 512; off <<= 1) {
        int u = (t >= off) ? tmp[t - off] : 0;
        __syncthreads();
        tmp[t] += u;
        __syncthreads();
    }
    offsets[t * N_WIN + w] = (t == 0) ? 0 : tmp[t - 1];
    if (t == 511) colsum[w] = tmp[511];
}

// 2b) exclusive scan of the 400 window totals -> winbase[0..400]
__global__ __launch_bounds__(512) void win_scan2_kernel(const int* __restrict__ colsum,
                                                        int* __restrict__ winbase) {
    __shared__ int tmp[512];
    const int t = threadIdx.x;
    tmp[t] = (t < N_WIN) ? colsum[t] : 0;
    __syncthreads();
#pragma unroll
    for (int off = 1; off < 512; off <<= 1) {
        int u = (t >= off) ? tmp[t - off] : 0;
        __syncthreads();
        tmp[t] += u;
        __syncthreads();
    }
    if (t < N_WIN) winbase[t] = (t == 0) ? 0 : tmp[t - 1];
    if (t == N_WIN - 1) winbase[N_WIN] = tmp[t];   // == N_EDGES
}

// 3) place edges window-major: wedge[p] = {dst, src}
__global__ __launch_bounds__(256) void win_place_kernel(const int* __restrict__ src,
                                                        const int* __restrict__ dst,
                                                        const int* __restrict__ offsets,
                                                        const int* __restrict__ winbase,
                                                        int2* __restrict__ wedge) {
    __shared__ int off[N_WIN];
    for (int i = threadIdx.x; i < N_WIN; i += 256)
        off[i] = offsets[blockIdx.x * N_WIN + i] + winbase[i];
    __syncthreads();
    const int e0 = blockIdx.x * BIN_CHUNK, e1 = e0 + BIN_CHUNK;
    for (int e = e0 + threadIdx.x; e < e1; e += 256) {
        int d = dst[e];
        int p = atomicAdd(&off[d / WIN_NODES], 1);
        wedge[p] = make_int2(d, src[e]);
    }
}

// 4) per-window degree: stream own bucket once, LDS counters, no global atomics
__global__ __launch_bounds__(256) void deg_win_kernel(const int2* __restrict__ wedge,
                                                      const int* __restrict__ winbase,
                                                      int* __restrict__ deg) {
    __shared__ int cnt[WIN_NODES];
    const int w = blockIdx.x;
    const int n0 = w * WIN_NODES;
    for (int i = threadIdx.x; i < WIN_NODES; i += 256) cnt[i] = 0;
    __syncthreads();
    const int b0 = winbase[w], b1 = winbase[w + 1];
    for (int e = b0 + threadIdx.x; e < b1; e += 256)
        atomicAdd(&cnt[wedge[e].x - n0], 1);
    __syncthreads();
    for (int i = threadIdx.x; i < WIN_NODES; i += 256) deg[n0 + i] = cnt[i];
}

// 6) windowed scatter: stream own bucket once, LDS cursors, contiguous csr range
__global__ __launch_bounds__(256) void scatter_win_kernel(const int2* __restrict__ wedge,
                                                          const int* __restrict__ winbase,
                                                          const int* __restrict__ posb,
                                                          int* __restrict__ csr_src) {
    __shared__ int wpos[WIN_NODES];
    const int w = blockIdx.x;
    const int n0 = w * WIN_NODES;
    for (int i = threadIdx.x; i < WIN_NODES; i += 256) wpos[i] = posb[n0 + i];
    __syncthreads();
    const int b0 = winbase[w], b1 = winbase[w + 1];
    for (int e = b0 + threadIdx.x; e < b1; e += 256) {
        int2 ed = wedge[e];
        int p = atomicAdd(&wpos[ed.x - n0], 1);
        csr_src[p] = ed.y;
    }
}

// ---------------------------------------------------------------------------
// 5) node-degree hierarchical scan (R2-confirmed)
// ---------------------------------------------------------------------------
__global__ __launch_bounds__(SCAN_BS) void scan_blocks_kernel(const int* __restrict__ deg,
                                                              int* __restrict__ scanned,
                                                              int* __restrict__ bsums) {
    __shared__ int tmp[SCAN_BS];
    const int t = threadIdx.x;
    const int i = blockIdx.x * SCAN_BS + t;
    int v = (i < N_NODES) ? deg[i] : 0;
    tmp[t] = v;
    __syncthreads();
#pragma unroll
    for (int off = 1; off < SCAN_BS; off <<= 1) {
        int u = (t >= off) ? tmp[t - off] : 0;
        __syncthreads();
        tmp[t] += u;
        __syncthreads();
    }
    if (i < N_NODES) scanned[i] = tmp[t];
    if (t == SCAN_BS - 1) bsums[blockIdx.x] = tmp[t];
}

__global__ __launch_bounds__(128) void scan_tops_kernel(int* __restrict__ bsums) {
    __shared__ int tmp[128];
    const int t = threadIdx.x;
    tmp[t] = (t < SCAN_NB) ? bsums[t] : 0;
    __syncthreads();
#pragma unroll
    for (int off = 1; off < 128; off <<= 1) {
        int u = (t >= off) ? tmp[t - off] : 0;
        __syncthreads();
        tmp[t] += u;
        __syncthreads();
    }
    if (t < SCAN_NB) bsums[t] = tmp[t];
}

__global__ __launch_bounds__(SCAN_BS) void scan_finalize_kernel(const int* __restrict__ deg,
                                                                const int* __restrict__ scanned,
                                                                const int* __restrict__ bsums,
                                                                int* __restrict__ row_ptr,
                                                                int* __restrict__ posb) {
    const int b = blockIdx.x;
    const int i = b * SCAN_BS + threadIdx.x;
    if (i >= N_NODES) return;
    const int off = (b > 0) ? bsums[b - 1] : 0;
    const int inc = off + scanned[i];
    row_ptr[i + 1] = inc;
    posb[i] = inc - deg[i];
    if (i == 0) row_ptr[0] = 0;
}

// ---------------------------------------------------------------------------
__global__ void f2h_kernel(const float* __restrict__ in, __half* __restrict__ out) {
    int t = blockIdx.x * blockDim.x + threadIdx.x;
    const int n8 = (N_NODES * HIDDEN) / 8;
    if (t >= n8) return;
    const float4* in4 = (const float4*)in;
    float4 a = in4[t * 2 + 0];
    float4 b = in4[t * 2 + 1];
    __half2* o2 = (__half2*)out;
    o2[t * 4 + 0] = __floats2half2_rn(a.x, a.y);
    o2[t * 4 + 1] = __floats2half2_rn(a.z, a.w);
    o2[t * 4 + 2] = __floats2half2_rn(b.x, b.y);
    o2[t * 4 + 3] = __floats2half2_rn(b.z, b.w);
}

__global__ void wconv_kernel(const float* __restrict__ w1, const float* __restrict__ w2,
                             __half* __restrict__ wt1, __half* __restrict__ wt2) {
    int t = blockIdx.x * blockDim.x + threadIdx.x;
    if (t >= N_LAYERS * HIDDEN * HIDDEN) return;
    int l = t / (HIDDEN * HIDDEN);
    int r = t - l * (HIDDEN * HIDDEN);
    int k = r / HIDDEN, n = r - k * HIDDEN;
    wt1[(size_t)l * HIDDEN * HIDDEN + n * HIDDEN + k] = __float2half(w1[t]);
    wt2[(size_t)l * HIDDEN * HIDDEN + n * HIDDEN + k] = __float2half(w2[t]);
}

// ---------------------------------------------------------------------------
// GIN aggregation (R7-confirmed): half8 loads, 4 rows per wave-load,
// shfl butterfly reduce, fp32 accumulate.
// ---------------------------------------------------------------------------
__global__ void gather_kernel(const __half* __restrict__ Xh, __half* __restrict__ Zh,
                              const int* __restrict__ row_ptr,
                              const int* __restrict__ csr_src) {
    int wave = (blockIdx.x * blockDim.x + threadIdx.x) >> 6;
    int lane = threadIdx.x & 63;
    if (wave >= N_NODES) return;
    const int grp = lane >> 4;
    const int m   = lane & 15;
    const half8* H8 = (const half8*)Xh;

    float8 acc = {0.f,0.f,0.f,0.f,0.f,0.f,0.f,0.f};
    int k = row_ptr[wave];
    const int end = row_ptr[wave + 1];

    for (; k + 8 <= end; k += 8) {
        int n0 = csr_src[k + grp];
        int n1 = csr_src[k + 4 + grp];
        half8 v0 = H8[(size_t)n0 * 16 + m];
        half8 v1 = H8[(size_t)n1 * 16 + m];
        acc += __builtin_convertvector(v0, float8);
        acc += __builtin_convertvector(v1, float8);
    }
    if (k + 4 <= end) {
        int n0 = csr_src[k + grp];
        half8 v0 = H8[(size_t)n0 * 16 + m];
        acc += __builtin_convertvector(v0, float8);
        k += 4;
    }
    int rem = end - k;
    if (grp < rem) {
        int n0 = csr_src[k + grp];
        half8 v0 = H8[(size_t)n0 * 16 + m];
        acc += __builtin_convertvector(v0, float8);
    }

#pragma unroll
    for (int j = 0; j < 8; ++j) acc[j] += __shfl_xor(acc[j], 16);
#pragma unroll
    for (int j = 0; j < 8; ++j) acc[j] += __shfl_xor(acc[j], 32);

    half8 sv = H8[(size_t)wave * 16 + m];
    acc += __builtin_convertvector(sv, float8);

    if (grp == 0) {
        half8 o = __builtin_convertvector(acc, half8);
        ((half8*)Zh)[(size_t)wave * 16 + m] = o;
    }
}

// ---------------------------------------------------------------------------
// MFMA GEMM (R6-verified layouts): C = relu(A @ W + bias), fp16 io/fp32 acc.
// ---------------------------------------------------------------------------
__global__ __launch_bounds__(256) void mm16_kernel(const __half* __restrict__ A,
                                                   const __half* __restrict__ Wt,
                                                   const float* __restrict__ bias,
                                                   __half* __restrict__ C16, int M) {
    const int wave = threadIdx.x >> 6;
    const int lane = threadIdx.x & 63;
    const int m = lane & 15;
    const int q = lane >> 4;
    const int row0 = blockIdx.x * 64 + wave * 16;

    int ra = row0 + m; if (ra > M - 1) ra = M - 1;
    const half8* Arow = (const half8*)(A + (size_t)ra * HIDDEN);
    half8 a0 = Arow[q];
    half8 a1 = Arow[4 + q];
    half8 a2 = Arow[8 + q];
    half8 a3 = Arow[12 + q];

#pragma unroll
    for (int ct = 0; ct < 8; ++ct) {
        const int n = ct * 16 + m;
        const half8* Wrow = (const half8*)(Wt + (size_t)n * HIDDEN);
        floatx4 acc = {0.f, 0.f, 0.f, 0.f};
        acc = __builtin_amdgcn_mfma_f32_16x16x32_f16(a0, Wrow[q],      acc, 0, 0, 0);
        acc = __builtin_amdgcn_mfma_f32_16x16x32_f16(a1, Wrow[4 + q],  acc, 0, 0, 0);
        acc = __builtin_amdgcn_mfma_f32_16x16x32_f16(a2, Wrow[8 + q],  acc, 0, 0, 0);
        acc = __builtin_amdgcn_mfma_f32_16x16x32_f16(a3, Wrow[12 + q], acc, 0, 0, 0);
        const float b = bias[n];
#pragma unroll
        for (int r = 0; r < 4; ++r) {
            int row = row0 + q * 4 + r;
            if (row < M) {
                float v = fmaxf(acc[r] + b, 0.f);
                C16[(size_t)row * HIDDEN + n] = __float2half(v);
            }
        }
    }
}

// ---------------------------------------------------------------------------
#define POOL_CHUNK 128
__global__ void pool_kernel(const __half* __restrict__ Xh, const int* __restrict__ batch,
                            float* __restrict__ pooled, int layer) {
    const int f = threadIdx.x;
    int start = blockIdx.x * POOL_CHUNK;
    int end = start + POOL_CHUNK;
    if (end > N_NODES) end = N_NODES;
    float acc = 0.f;
    int gcur = batch[start];
    for (int n = start; n < end; ++n) {
        int g = batch[n];
        if (g != gcur) {
            atomicAdd(&pooled[(size_t)gcur * (HIDDEN * N_LAYERS) + layer * HIDDEN + f], acc);
            acc = 0.f;
            gcur = g;
        }
        acc += __half2float(Xh[(size_t)n * HIDDEN + f]);
    }
    atomicAdd(&pooled[(size_t)gcur * (HIDDEN * N_LAYERS) + layer * HIDDEN + f], acc);
}

// ---------------------------------------------------------------------------
__global__ __launch_bounds__(128) void cls_kernel(const float* __restrict__ pooled,
                                                  const float* __restrict__ w1,
                                                  const float* __restrict__ b1,
                                                  const float* __restrict__ w2,
                                                  const float* __restrict__ b2,
                                                  const float* __restrict__ w3,
                                                  const float* __restrict__ b3,
                                                  float* __restrict__ out) {
    __shared__ float hin[HIDDEN * N_LAYERS];
    __shared__ float h1[HIDDEN];
    __shared__ float red[HIDDEN];
    const int g = blockIdx.x;
    const int t = threadIdx.x;

    for (int i = t; i < HIDDEN * N_LAYERS; i += 128)
        hin[i] = pooled[(size_t)g * (HIDDEN * N_LAYERS) + i];
    __syncthreads();

    float s = 0.f;
    for (int k = 0; k < HIDDEN * N_LAYERS; ++k) s += hin[k] * w1[(size_t)k * HIDDEN + t];
    s = fmaxf(s + b1[t], 0.f);
    h1[t] = s;
    __syncthreads();

    float s2 = 0.f;
    for (int k = 0; k < HIDDEN; ++k) s2 += h1[k] * w2[(size_t)k * HIDDEN + t];
    s2 = fmaxf(s2 + b2[t], 0.f);

    red[t] = s2 * w3[t];
    __syncthreads();
    for (int off = 64; off > 0; off >>= 1) {
        if (t < off) red[t] += red[t + off];
        __syncthreads();
    }
    if (t == 0) out[g] = red[0] + b3[0];
}

// ---------------------------------------------------------------------------
extern "C" void kernel_launch(void* const* d_in, const int* in_sizes, int n_in,
                              void* d_out, int out_size, void* d_ws, size_t ws_size,
                              hipStream_t stream) {
    const float* X     = (const float*)d_in[0];
    const int*   ei    = (const int*)d_in[1];
    const int*   batch = (const int*)d_in[2];
    const float* w1all = (const float*)d_in[3];
    const float* b1all = (const float*)d_in[4];
    const float* w2all = (const float*)d_in[5];
    const float* b2all = (const float*)d_in[6];
    const float* cw1   = (const float*)d_in[7];
    const float* cb1   = (const float*)d_in[8];
    const float* cw2   = (const float*)d_in[9];
    const float* cb2   = (const float*)d_in[10];
    const float* cw3   = (const float*)d_in[11];
    const float* cb3   = (const float*)d_in[12];
    float* out = (float*)d_out;

    const int* src = ei;
    const int* dst = ei + N_EDGES;

    char* p = (char*)d_ws;
    auto alloc = [&](size_t bytes) {
        char* r = p;
        p += (bytes + 255) & ~(size_t)255;
        return r;
    };
    __half* hA      = (__half*)alloc((size_t)N_NODES * HIDDEN * sizeof(__half));
    __half* hB      = (__half*)alloc((size_t)N_NODES * HIDDEN * sizeof(__half));
    __half* zh      = (__half*)alloc((size_t)N_NODES * HIDDEN * sizeof(__half));
    __half* m1h     = (__half*)alloc((size_t)N_NODES * HIDDEN * sizeof(__half));
    __half* wt1     = (__half*)alloc((size_t)N_LAYERS * HIDDEN * HIDDEN * sizeof(__half));
    __half* wt2     = (__half*)alloc((size_t)N_LAYERS * HIDDEN * HIDDEN * sizeof(__half));
    int2*   wedge   = (int2*)alloc((size_t)N_EDGES * sizeof(int2));
    int*    csr     = (int*)alloc((size_t)N_EDGES * sizeof(int));
    int*    rowp    = (int*)alloc((size_t)(N_NODES + 1) * sizeof(int));
    int*    posb    = (int*)alloc((size_t)N_NODES * sizeof(int));
    int*    deg     = (int*)alloc((size_t)N_NODES * sizeof(int));
    int*    scanned = (int*)alloc((size_t)N_NODES * sizeof(int));
    int*    bsums   = (int*)alloc((size_t)SCAN_NB * sizeof(int));
    int*    counts  = (int*)alloc((size_t)BIN_BLOCKS * N_WIN * sizeof(int));
    int*    offsets = (int*)alloc((size_t)BIN_BLOCKS * N_WIN * sizeof(int));
    int*    colsum  = (int*)alloc((size_t)N_WIN * sizeof(int));
    int*    winbase = (int*)alloc((size_t)(N_WIN + 1) * sizeof(int));
    float*  pooled  = (float*)alloc((size_t)N_GRAPHS * HIDDEN * N_LAYERS * sizeof(float));

    hipMemsetAsync(pooled, 0, (size_t)N_GRAPHS * HIDDEN * N_LAYERS * sizeof(float), stream);

    // CSR build: 400-way counting sort, window-local deg/scatter
    win_count_kernel<<<BIN_BLOCKS, 256, 0, stream>>>(dst, counts);
    win_scan1_kernel<<<N_WIN, 512, 0, stream>>>(counts, offsets, colsum);
    win_scan2_kernel<<<1, 512, 0, stream>>>(colsum, winbase);
    win_place_kernel<<<BIN_BLOCKS, 256, 0, stream>>>(src, dst, offsets, winbase, wedge);
    deg_win_kernel<<<N_WIN, 256, 0, stream>>>(wedge, winbase, deg);
    scan_blocks_kernel<<<SCAN_NB, SCAN_BS, 0, stream>>>(deg, scanned, bsums);
    scan_tops_kernel<<<1, 128, 0, stream>>>(bsums);
    scan_finalize_kernel<<<SCAN_NB, SCAN_BS, 0, stream>>>(deg, scanned, bsums, rowp, posb);
    scatter_win_kernel<<<N_WIN, 256, 0, stream>>>(wedge, winbase, posb, csr);

    const int f2h_grid = ((N_NODES * HIDDEN / 8) + 255) / 256;
    f2h_kernel<<<f2h_grid, 256, 0, stream>>>(X, hA);
    wconv_kernel<<<(N_LAYERS * HIDDEN * HIDDEN + 255) / 256, 256, 0, stream>>>(w1all, w2all, wt1, wt2);

    const int mm_grid   = (N_NODES + 63) / 64;
    const int gat_grid  = (N_NODES + 3) / 4;
    const int pool_grid = (N_NODES + POOL_CHUNK - 1) / POOL_CHUNK;

    __half* hcur = hA;
    for (int l = 0; l < N_LAYERS; ++l) {
        __half* hnext = (l & 1) ? hA : hB;
        gather_kernel<<<gat_grid, 256, 0, stream>>>(hcur, zh, rowp, csr);
        mm16_kernel<<<mm_grid, 256, 0, stream>>>(zh,
                                                 wt1 + (size_t)l * HIDDEN * HIDDEN,
                                                 b1all + (size_t)l * HIDDEN,
                                                 m1h, N_NODES);
        mm16_kernel<<<mm_grid, 256, 0, stream>>>(m1h,
                                                 wt2 + (size_t)l * HIDDEN * HIDDEN,
                                                 b2all + (size_t)l * HIDDEN,
                                                 hnext, N_NODES);
        pool_kernel<<<pool_grid, POOL_CHUNK, 0, stream>>>(hnext, batch, pooled, l);
        hcur = hnext;
    }

    cls_kernel<<<N_GRAPHS, 128, 0, stream>>>(pooled, cw1, cb1, cw2, cb2, cw3, cb3, out);
}

// Round 10
// 653.248 us; speedup vs baseline: 1.4316x; 1.0789x over previous
//
#include <hip/hip_runtime.h>
#include <hip/hip_fp16.h>
#include <cstddef>
#include <cstdint>

#define N_NODES   100000
#define N_EDGES   1600000
#define N_GRAPHS  512
#define HIDDEN    128
#define N_LAYERS  3

// 400-way counting sort (R9-confirmed: write-amp gone, no re-read)
#define N_WIN      400
#define WIN_NODES  (N_NODES / N_WIN)        // 250
#define BIN_BLOCKS 512
#define BIN_CHUNK  (N_EDGES / BIN_BLOCKS)   // 3125 exactly

typedef _Float16 half8 __attribute__((ext_vector_type(8)));
typedef float    float8 __attribute__((ext_vector_type(8)));
typedef float    floatx4 __attribute__((ext_vector_type(4)));

// ---------------------------------------------------------------------------
// 1) per-block 400-bin histogram of dst windows
// ---------------------------------------------------------------------------
__global__ __launch_bounds__(256) void win_count_kernel(const int* __restrict__ dst,
                                                        int* __restrict__ counts) {
    __shared__ int cs[N_WIN];
    for (int i = threadIdx.x; i < N_WIN; i += 256) cs[i] = 0;
    __syncthreads();
    const int e0 = blockIdx.x * BIN_CHUNK, e1 = e0 + BIN_CHUNK;
    for (int e = e0 + threadIdx.x; e < e1; e += 256)
        atomicAdd(&cs[dst[e] / WIN_NODES], 1);
    __syncthreads();
    for (int i = threadIdx.x; i < N_WIN; i += 256)
        counts[blockIdx.x * N_WIN + i] = cs[i];
}

// 2a) column scan: offsets[b][w] = prefix_b(counts[.][w]); colsum[w] = total
__global__ __launch_bounds__(512) void win_scan1_kernel(const int* __restrict__ counts,
                                                        int* __restrict__ offsets,
                                                        int* __restrict__ colsum) {
    __shared__ int tmp[512];
    const int w = blockIdx.x;
    const int t = threadIdx.x;
    tmp[t] = counts[t * N_WIN + w];
    __syncthreads();
#pragma unroll
    for (int off = 1; off < 512; off <<= 1) {
        int u = (t >= off) ? tmp[t - off] : 0;
        __syncthreads();
        tmp[t] += u;
        __syncthreads();
    }
    offsets[t * N_WIN + w] = (t == 0) ? 0 : tmp[t - 1];
    if (t == 511) colsum[w] = tmp[511];
}

// 2b) exclusive scan of the 400 window totals -> winbase[0..400]
__global__ __launch_bounds__(512) void win_scan2_kernel(const int* __restrict__ colsum,
                                                        int* __restrict__ winbase) {
    __shared__ int tmp[512];
    const int t = threadIdx.x;
    tmp[t] = (t < N_WIN) ? colsum[t] : 0;
    __syncthreads();
#pragma unroll
    for (int off = 1; off < 512; off <<= 1) {
        int u = (t >= off) ? tmp[t - off] : 0;
        __syncthreads();
        tmp[t] += u;
        __syncthreads();
    }
    if (t < N_WIN) winbase[t] = (t == 0) ? 0 : tmp[t - 1];
    if (t == N_WIN - 1) winbase[N_WIN] = tmp[t];   // == N_EDGES
}

// 3) place edges window-major: wedge[p] = {dst, src}
__global__ __launch_bounds__(256) void win_place_kernel(const int* __restrict__ src,
                                                        const int* __restrict__ dst,
                                                        const int* __restrict__ offsets,
                                                        const int* __restrict__ winbase,
                                                        int2* __restrict__ wedge) {
    __shared__ int off[N_WIN];
    for (int i = threadIdx.x; i < N_WIN; i += 256)
        off[i] = offsets[blockIdx.x * N_WIN + i] + winbase[i];
    __syncthreads();
    const int e0 = blockIdx.x * BIN_CHUNK, e1 = e0 + BIN_CHUNK;
    for (int e = e0 + threadIdx.x; e < e1; e += 256) {
        int d = dst[e];
        int p = atomicAdd(&off[d / WIN_NODES], 1);
        wedge[p] = make_int2(d, src[e]);
    }
}

// 4) fused per-window CSR: count (LDS) -> in-block scan -> row_ptr -> scatter.
// Replaces deg + 3-kernel global scan + scatter (R9 structure, consolidated).
__global__ __launch_bounds__(256) void win_csr_kernel(const int2* __restrict__ wedge,
                                                      const int* __restrict__ winbase,
                                                      int* __restrict__ row_ptr,
                                                      int* __restrict__ csr_src) {
    __shared__ int cnt[WIN_NODES];
    __shared__ int tmp[256];
    const int w = blockIdx.x, n0 = w * WIN_NODES, t = threadIdx.x;
    for (int i = t; i < WIN_NODES; i += 256) cnt[i] = 0;
    __syncthreads();
    const int b0 = winbase[w], b1 = winbase[w + 1];
    for (int e = b0 + t; e < b1; e += 256)
        atomicAdd(&cnt[wedge[e].x - n0], 1);
    __syncthreads();
    tmp[t] = (t < WIN_NODES) ? cnt[t] : 0;
    __syncthreads();
#pragma unroll
    for (int off = 1; off < 256; off <<= 1) {
        int u = (t >= off) ? tmp[t - off] : 0;
        __syncthreads();
        tmp[t] += u;
        __syncthreads();
    }
    const int excl = (t == 0) ? 0 : tmp[t - 1];
    if (t < WIN_NODES) {
        row_ptr[n0 + t] = b0 + excl;   // window w+1's entry supplies [n0+250]
        cnt[t] = b0 + excl;            // reuse as scatter cursor
    }
    if (w == N_WIN - 1 && t == 0) row_ptr[N_NODES] = winbase[N_WIN];
    __syncthreads();
    for (int e = b0 + t; e < b1; e += 256) {
        int2 ed = wedge[e];
        int p = atomicAdd(&cnt[ed.x - n0], 1);
        csr_src[p] = ed.y;
    }
}

// ---------------------------------------------------------------------------
__global__ void f2h_kernel(const float* __restrict__ in, __half* __restrict__ out) {
    int t = blockIdx.x * blockDim.x + threadIdx.x;
    const int n8 = (N_NODES * HIDDEN) / 8;
    if (t >= n8) return;
    const float4* in4 = (const float4*)in;
    float4 a = in4[t * 2 + 0];
    float4 b = in4[t * 2 + 1];
    __half2* o2 = (__half2*)out;
    o2[t * 4 + 0] = __floats2half2_rn(a.x, a.y);
    o2[t * 4 + 1] = __floats2half2_rn(a.z, a.w);
    o2[t * 4 + 2] = __floats2half2_rn(b.x, b.y);
    o2[t * 4 + 3] = __floats2half2_rn(b.z, b.w);
}

__global__ void wconv_kernel(const float* __restrict__ w1, const float* __restrict__ w2,
                             __half* __restrict__ wt1, __half* __restrict__ wt2) {
    int t = blockIdx.x * blockDim.x + threadIdx.x;
    if (t >= N_LAYERS * HIDDEN * HIDDEN) return;
    int l = t / (HIDDEN * HIDDEN);
    int r = t - l * (HIDDEN * HIDDEN);
    int k = r / HIDDEN, n = r - k * HIDDEN;
    wt1[(size_t)l * HIDDEN * HIDDEN + n * HIDDEN + k] = __float2half(w1[t]);
    wt2[(size_t)l * HIDDEN * HIDDEN + n * HIDDEN + k] = __float2half(w2[t]);
}

// ---------------------------------------------------------------------------
// GIN aggregation: half8 loads, 4 rows/wave-load, unroll-16 => 4 independent
// load instructions (16 rows) in flight per wave (R9: MLP-limited at 3.5TB/s).
// ---------------------------------------------------------------------------
__global__ void gather_kernel(const __half* __restrict__ Xh, __half* __restrict__ Zh,
                              const int* __restrict__ row_ptr,
                              const int* __restrict__ csr_src) {
    int wave = (blockIdx.x * blockDim.x + threadIdx.x) >> 6;
    int lane = threadIdx.x & 63;
    if (wave >= N_NODES) return;
    const int grp = lane >> 4;
    const int m   = lane & 15;
    const half8* H8 = (const half8*)Xh;

    float8 acc = {0.f,0.f,0.f,0.f,0.f,0.f,0.f,0.f};
    int k = row_ptr[wave];
    const int end = row_ptr[wave + 1];

    for (; k + 16 <= end; k += 16) {
        int n0 = csr_src[k + grp];
        int n1 = csr_src[k + 4 + grp];
        int n2 = csr_src[k + 8 + grp];
        int n3 = csr_src[k + 12 + grp];
        half8 v0 = H8[(size_t)n0 * 16 + m];
        half8 v1 = H8[(size_t)n1 * 16 + m];
        half8 v2 = H8[(size_t)n2 * 16 + m];
        half8 v3 = H8[(size_t)n3 * 16 + m];
        acc += __builtin_convertvector(v0, float8);
        acc += __builtin_convertvector(v1, float8);
        acc += __builtin_convertvector(v2, float8);
        acc += __builtin_convertvector(v3, float8);
    }
    if (k + 8 <= end) {
        int n0 = csr_src[k + grp];
        int n1 = csr_src[k + 4 + grp];
        half8 v0 = H8[(size_t)n0 * 16 + m];
        half8 v1 = H8[(size_t)n1 * 16 + m];
        acc += __builtin_convertvector(v0, float8);
        acc += __builtin_convertvector(v1, float8);
        k += 8;
    }
    if (k + 4 <= end) {
        int n0 = csr_src[k + grp];
        half8 v0 = H8[(size_t)n0 * 16 + m];
        acc += __builtin_convertvector(v0, float8);
        k += 4;
    }
    int rem = end - k;
    if (grp < rem) {
        int n0 = csr_src[k + grp];
        half8 v0 = H8[(size_t)n0 * 16 + m];
        acc += __builtin_convertvector(v0, float8);
    }

#pragma unroll
    for (int j = 0; j < 8; ++j) acc[j] += __shfl_xor(acc[j], 16);
#pragma unroll
    for (int j = 0; j < 8; ++j) acc[j] += __shfl_xor(acc[j], 32);

    half8 sv = H8[(size_t)wave * 16 + m];
    acc += __builtin_convertvector(sv, float8);

    if (grp == 0) {
        half8 o = __builtin_convertvector(acc, half8);
        ((half8*)Zh)[(size_t)wave * 16 + m] = o;
    }
}

// ---------------------------------------------------------------------------
// Fused MLP: C = relu(relu(A@W1+b1)@W2+b2), fp16 io, fp32 acc.
// Stage-1 result crosses C-layout -> A-layout via wave-local padded LDS
// (pad +8 halves: ds_read_b128 is 2-way = free; no barriers, wave-private).
// ---------------------------------------------------------------------------
#define LDSPAD 136
__global__ __launch_bounds__(256) void mmfused_kernel(const __half* __restrict__ A,
                                                      const __half* __restrict__ Wt1,
                                                      const float* __restrict__ b1,
                                                      const __half* __restrict__ Wt2,
                                                      const float* __restrict__ b2,
                                                      __half* __restrict__ C16, int M) {
    __shared__ _Float16 h1s[4][16 * LDSPAD];   // 4 x 4352 B, per-wave scratch
    const int wave = threadIdx.x >> 6;
    const int lane = threadIdx.x & 63;
    const int m = lane & 15;
    const int q = lane >> 4;
    const int row0 = blockIdx.x * 64 + wave * 16;
    _Float16* Hs = h1s[wave];

    int ra = row0 + m; if (ra > M - 1) ra = M - 1;
    const half8* Arow = (const half8*)(A + (size_t)ra * HIDDEN);
    half8 a0 = Arow[q];
    half8 a1 = Arow[4 + q];
    half8 a2 = Arow[8 + q];
    half8 a3 = Arow[12 + q];

    // stage 1: h1 -> wave-local LDS
#pragma unroll
    for (int ct = 0; ct < 8; ++ct) {
        const int n = ct * 16 + m;
        const half8* Wrow = (const half8*)(Wt1 + (size_t)n * HIDDEN);
        floatx4 acc = {0.f, 0.f, 0.f, 0.f};
        acc = __builtin_amdgcn_mfma_f32_16x16x32_f16(a0, Wrow[q],      acc, 0, 0, 0);
        acc = __builtin_amdgcn_mfma_f32_16x16x32_f16(a1, Wrow[4 + q],  acc, 0, 0, 0);
        acc = __builtin_amdgcn_mfma_f32_16x16x32_f16(a2, Wrow[8 + q],  acc, 0, 0, 0);
        acc = __builtin_amdgcn_mfma_f32_16x16x32_f16(a3, Wrow[12 + q], acc, 0, 0, 0);
        const float bb = b1[n];
#pragma unroll
        for (int r = 0; r < 4; ++r)
            Hs[(q * 4 + r) * LDSPAD + n] = (_Float16)fmaxf(acc[r] + bb, 0.f);
    }
    // wave-private LDS RAW: DS pipe is in-order per wave; no __syncthreads.
    half8 c0 = *(const half8*)&Hs[m * LDSPAD + q * 8];
    half8 c1 = *(const half8*)&Hs[m * LDSPAD + 32 + q * 8];
    half8 c2 = *(const half8*)&Hs[m * LDSPAD + 64 + q * 8];
    half8 c3 = *(const half8*)&Hs[m * LDSPAD + 96 + q * 8];

    // stage 2
#pragma unroll
    for (int ct = 0; ct < 8; ++ct) {
        const int n = ct * 16 + m;
        const half8* Wrow = (const half8*)(Wt2 + (size_t)n * HIDDEN);
        floatx4 acc = {0.f, 0.f, 0.f, 0.f};
        acc = __builtin_amdgcn_mfma_f32_16x16x32_f16(c0, Wrow[q],      acc, 0, 0, 0);
        acc = __builtin_amdgcn_mfma_f32_16x16x32_f16(c1, Wrow[4 + q],  acc, 0, 0, 0);
        acc = __builtin_amdgcn_mfma_f32_16x16x32_f16(c2, Wrow[8 + q],  acc, 0, 0, 0);
        acc = __builtin_amdgcn_mfma_f32_16x16x32_f16(c3, Wrow[12 + q], acc, 0, 0, 0);
        const float bb = b2[n];
#pragma unroll
        for (int r = 0; r < 4; ++r) {
            int row = row0 + q * 4 + r;
            if (row < M) {
                float v = fmaxf(acc[r] + bb, 0.f);
                C16[(size_t)row * HIDDEN + n] = __float2half(v);
            }
        }
    }
}

// ---------------------------------------------------------------------------
#define POOL_CHUNK 128
__global__ void pool_kernel(const __half* __restrict__ Xh, const int* __restrict__ batch,
                            float* __restrict__ pooled, int layer) {
    const int f = threadIdx.x;
    int start = blockIdx.x * POOL_CHUNK;
    int end = start + POOL_CHUNK;
    if (end > N_NODES) end = N_NODES;
    float acc = 0.f;
    int gcur = batch[start];
    for (int n = start; n < end; ++n) {
        int g = batch[n];
        if (g != gcur) {
            atomicAdd(&pooled[(size_t)gcur * (HIDDEN * N_LAYERS) + layer * HIDDEN + f], acc);
            acc = 0.f;
            gcur = g;
        }
        acc += __half2float(Xh[(size_t)n * HIDDEN + f]);
    }
    atomicAdd(&pooled[(size_t)gcur * (HIDDEN * N_LAYERS) + layer * HIDDEN + f], acc);
}

// ---------------------------------------------------------------------------
__global__ __launch_bounds__(128) void cls_kernel(const float* __restrict__ pooled,
                                                  const float* __restrict__ w1,
                                                  const float* __restrict__ b1,
                                                  const float* __restrict__ w2,
                                                  const float* __restrict__ b2,
                                                  const float* __restrict__ w3,
                                                  const float* __restrict__ b3,
                                                  float* __restrict__ out) {
    __shared__ float hin[HIDDEN * N_LAYERS];
    __shared__ float h1[HIDDEN];
    __shared__ float red[HIDDEN];
    const int g = blockIdx.x;
    const int t = threadIdx.x;

    for (int i = t; i < HIDDEN * N_LAYERS; i += 128)
        hin[i] = pooled[(size_t)g * (HIDDEN * N_LAYERS) + i];
    __syncthreads();

    float s = 0.f;
    for (int k = 0; k < HIDDEN * N_LAYERS; ++k) s += hin[k] * w1[(size_t)k * HIDDEN + t];
    s = fmaxf(s + b1[t], 0.f);
    h1[t] = s;
    __syncthreads();

    float s2 = 0.f;
    for (int k = 0; k < HIDDEN; ++k) s2 += h1[k] * w2[(size_t)k * HIDDEN + t];
    s2 = fmaxf(s2 + b2[t], 0.f);

    red[t] = s2 * w3[t];
    __syncthreads();
    for (int off = 64; off > 0; off >>= 1) {
        if (t < off) red[t] += red[t + off];
        __syncthreads();
    }
    if (t == 0) out[g] = red[0] + b3[0];
}

// ---------------------------------------------------------------------------
extern "C" void kernel_launch(void* const* d_in, const int* in_sizes, int n_in,
                              void* d_out, int out_size, void* d_ws, size_t ws_size,
                              hipStream_t stream) {
    const float* X     = (const float*)d_in[0];
    const int*   ei    = (const int*)d_in[1];
    const int*   batch = (const int*)d_in[2];
    const float* w1all = (const float*)d_in[3];
    const float* b1all = (const float*)d_in[4];
    const float* w2all = (const float*)d_in[5];
    const float* b2all = (const float*)d_in[6];
    const float* cw1   = (const float*)d_in[7];
    const float* cb1   = (const float*)d_in[8];
    const float* cw2   = (const float*)d_in[9];
    const float* cb2   = (const float*)d_in[10];
    const float* cw3   = (const float*)d_in[11];
    const float* cb3   = (const float*)d_in[12];
    float* out = (float*)d_out;

    const int* src = ei;
    const int* dst = ei + N_EDGES;

    char* p = (char*)d_ws;
    auto alloc = [&](size_t bytes) {
        char* r = p;
        p += (bytes + 255) & ~(size_t)255;
        return r;
    };
    __half* hA      = (__half*)alloc((size_t)N_NODES * HIDDEN * sizeof(__half));
    __half* hB      = (__half*)alloc((size_t)N_NODES * HIDDEN * sizeof(__half));
    __half* zh      = (__half*)alloc((size_t)N_NODES * HIDDEN * sizeof(__half));
    __half* wt1     = (__half*)alloc((size_t)N_LAYERS * HIDDEN * HIDDEN * sizeof(__half));
    __half* wt2     = (__half*)alloc((size_t)N_LAYERS * HIDDEN * HIDDEN * sizeof(__half));
    int2*   wedge   = (int2*)alloc((size_t)N_EDGES * sizeof(int2));
    int*    csr     = (int*)alloc((size_t)N_EDGES * sizeof(int));
    int*    rowp    = (int*)alloc((size_t)(N_NODES + 1) * sizeof(int));
    int*    counts  = (int*)alloc((size_t)BIN_BLOCKS * N_WIN * sizeof(int));
    int*    offsets = (int*)alloc((size_t)BIN_BLOCKS * N_WIN * sizeof(int));
    int*    colsum  = (int*)alloc((size_t)N_WIN * sizeof(int));
    int*    winbase = (int*)alloc((size_t)(N_WIN + 1) * sizeof(int));
    float*  pooled  = (float*)alloc((size_t)N_GRAPHS * HIDDEN * N_LAYERS * sizeof(float));

    hipMemsetAsync(pooled, 0, (size_t)N_GRAPHS * HIDDEN * N_LAYERS * sizeof(float), stream);

    // CSR build: 400-way counting sort + fused per-window csr
    win_count_kernel<<<BIN_BLOCKS, 256, 0, stream>>>(dst, counts);
    win_scan1_kernel<<<N_WIN, 512, 0, stream>>>(counts, offsets, colsum);
    win_scan2_kernel<<<1, 512, 0, stream>>>(colsum, winbase);
    win_place_kernel<<<BIN_BLOCKS, 256, 0, stream>>>(src, dst, offsets, winbase, wedge);
    win_csr_kernel<<<N_WIN, 256, 0, stream>>>(wedge, winbase, rowp, csr);

    const int f2h_grid = ((N_NODES * HIDDEN / 8) + 255) / 256;
    f2h_kernel<<<f2h_grid, 256, 0, stream>>>(X, hA);
    wconv_kernel<<<(N_LAYERS * HIDDEN * HIDDEN + 255) / 256, 256, 0, stream>>>(w1all, w2all, wt1, wt2);

    const int mm_grid   = (N_NODES + 63) / 64;
    const int gat_grid  = (N_NODES + 3) / 4;
    const int pool_grid = (N_NODES + POOL_CHUNK - 1) / POOL_CHUNK;

    __half* hcur = hA;
    for (int l = 0; l < N_LAYERS; ++l) {
        __half* hnext = (l & 1) ? hA : hB;
        gather_kernel<<<gat_grid, 256, 0, stream>>>(hcur, zh, rowp, csr);
        mmfused_kernel<<<mm_grid, 256, 0, stream>>>(zh,
                                                    wt1 + (size_t)l * HIDDEN * HIDDEN,
                                                    b1all + (size_t)l * HIDDEN,
                                                    wt2 + (size_t)l * HIDDEN * HIDDEN,
                                                    b2all + (size_t)l * HIDDEN,
                                                    hnext, N_NODES);
        pool_kernel<<<pool_grid, POOL_CHUNK, 0, stream>>>(hnext, batch, pooled, l);
        hcur = hnext;
    }

    cls_kernel<<<N_GRAPHS, 128, 0, stream>>>(pooled, cw1, cb1, cw2, cb2, cw3, cb3, out);
}

// Round 11
// 589.160 us; speedup vs baseline: 1.5873x; 1.1088x over previous
//
#include <hip/hip_runtime.h>
#include <hip/hip_fp16.h>
#include <cstddef>
#include <cstdint>

#define N_NODES   100000
#define N_EDGES   1600000
#define N_GRAPHS  512
#define HIDDEN    128
#define N_LAYERS  3

// 400-way counting sort (R9-confirmed: write-amp gone, no re-read)
#define N_WIN      400
#define WIN_NODES  (N_NODES / N_WIN)        // 250
#define BIN_BLOCKS 512
#define BIN_CHUNK  (N_EDGES / BIN_BLOCKS)   // 3125 exactly

typedef _Float16 half8 __attribute__((ext_vector_type(8)));
typedef float    float8 __attribute__((ext_vector_type(8)));
typedef float    floatx4 __attribute__((ext_vector_type(4)));

// ---------------------------------------------------------------------------
// 1) per-block 400-bin histogram of dst windows
// ---------------------------------------------------------------------------
__global__ __launch_bounds__(256) void win_count_kernel(const int* __restrict__ dst,
                                                        int* __restrict__ counts) {
    __shared__ int cs[N_WIN];
    for (int i = threadIdx.x; i < N_WIN; i += 256) cs[i] = 0;
    __syncthreads();
    const int e0 = blockIdx.x * BIN_CHUNK, e1 = e0 + BIN_CHUNK;
    for (int e = e0 + threadIdx.x; e < e1; e += 256)
        atomicAdd(&cs[dst[e] / WIN_NODES], 1);
    __syncthreads();
    for (int i = threadIdx.x; i < N_WIN; i += 256)
        counts[blockIdx.x * N_WIN + i] = cs[i];
}

// 2a) column scan: offsets[b][w] = prefix_b(counts[.][w]); colsum[w] = total
__global__ __launch_bounds__(512) void win_scan1_kernel(const int* __restrict__ counts,
                                                        int* __restrict__ offsets,
                                                        int* __restrict__ colsum) {
    __shared__ int tmp[512];
    const int w = blockIdx.x;
    const int t = threadIdx.x;
    tmp[t] = counts[t * N_WIN + w];
    __syncthreads();
#pragma unroll
    for (int off = 1; off < 512; off <<= 1) {
        int u = (t >= off) ? tmp[t - off] : 0;
        __syncthreads();
        tmp[t] += u;
        __syncthreads();
    }
    offsets[t * N_WIN + w] = (t == 0) ? 0 : tmp[t - 1];
    if (t == 511) colsum[w] = tmp[511];
}

// 2b) exclusive scan of the 400 window totals -> winbase[0..400]
__global__ __launch_bounds__(512) void win_scan2_kernel(const int* __restrict__ colsum,
                                                        int* __restrict__ winbase) {
    __shared__ int tmp[512];
    const int t = threadIdx.x;
    tmp[t] = (t < N_WIN) ? colsum[t] : 0;
    __syncthreads();
#pragma unroll
    for (int off = 1; off < 512; off <<= 1) {
        int u = (t >= off) ? tmp[t - off] : 0;
        __syncthreads();
        tmp[t] += u;
        __syncthreads();
    }
    if (t < N_WIN) winbase[t] = (t == 0) ? 0 : tmp[t - 1];
    if (t == N_WIN - 1) winbase[N_WIN] = tmp[t];   // == N_EDGES
}

// 3) place edges window-major: wedge[p] = {dst, src}
__global__ __launch_bounds__(256) void win_place_kernel(const int* __restrict__ src,
                                                        const int* __restrict__ dst,
                                                        const int* __restrict__ offsets,
                                                        const int* __restrict__ winbase,
                                                        int2* __restrict__ wedge) {
    __shared__ int off[N_WIN];
    for (int i = threadIdx.x; i < N_WIN; i += 256)
        off[i] = offsets[blockIdx.x * N_WIN + i] + winbase[i];
    __syncthreads();
    const int e0 = blockIdx.x * BIN_CHUNK, e1 = e0 + BIN_CHUNK;
    for (int e = e0 + threadIdx.x; e < e1; e += 256) {
        int d = dst[e];
        int p = atomicAdd(&off[d / WIN_NODES], 1);
        wedge[p] = make_int2(d, src[e]);
    }
}

// 4) fused per-window CSR: count (LDS) -> in-block scan -> row_ptr -> scatter.
__global__ __launch_bounds__(256) void win_csr_kernel(const int2* __restrict__ wedge,
                                                      const int* __restrict__ winbase,
                                                      int* __restrict__ row_ptr,
                                                      int* __restrict__ csr_src) {
    __shared__ int cnt[WIN_NODES];
    __shared__ int tmp[256];
    const int w = blockIdx.x, n0 = w * WIN_NODES, t = threadIdx.x;
    for (int i = t; i < WIN_NODES; i += 256) cnt[i] = 0;
    __syncthreads();
    const int b0 = winbase[w], b1 = winbase[w + 1];
    for (int e = b0 + t; e < b1; e += 256)
        atomicAdd(&cnt[wedge[e].x - n0], 1);
    __syncthreads();
    tmp[t] = (t < WIN_NODES) ? cnt[t] : 0;
    __syncthreads();
#pragma unroll
    for (int off = 1; off < 256; off <<= 1) {
        int u = (t >= off) ? tmp[t - off] : 0;
        __syncthreads();
        tmp[t] += u;
        __syncthreads();
    }
    const int excl = (t == 0) ? 0 : tmp[t - 1];
    if (t < WIN_NODES) {
        row_ptr[n0 + t] = b0 + excl;
        cnt[t] = b0 + excl;
    }
    if (w == N_WIN - 1 && t == 0) row_ptr[N_NODES] = winbase[N_WIN];
    __syncthreads();
    for (int e = b0 + t; e < b1; e += 256) {
        int2 ed = wedge[e];
        int p = atomicAdd(&cnt[ed.x - n0], 1);
        csr_src[p] = ed.y;
    }
}

// ---------------------------------------------------------------------------
__global__ void f2h_kernel(const float* __restrict__ in, __half* __restrict__ out) {
    int t = blockIdx.x * blockDim.x + threadIdx.x;
    const int n8 = (N_NODES * HIDDEN) / 8;
    if (t >= n8) return;
    const float4* in4 = (const float4*)in;
    float4 a = in4[t * 2 + 0];
    float4 b = in4[t * 2 + 1];
    __half2* o2 = (__half2*)out;
    o2[t * 4 + 0] = __floats2half2_rn(a.x, a.y);
    o2[t * 4 + 1] = __floats2half2_rn(a.z, a.w);
    o2[t * 4 + 2] = __floats2half2_rn(b.x, b.y);
    o2[t * 4 + 3] = __floats2half2_rn(b.z, b.w);
}

__global__ void wconv_kernel(const float* __restrict__ w1, const float* __restrict__ w2,
                             __half* __restrict__ wt1, __half* __restrict__ wt2) {
    int t = blockIdx.x * blockDim.x + threadIdx.x;
    if (t >= N_LAYERS * HIDDEN * HIDDEN) return;
    int l = t / (HIDDEN * HIDDEN);
    int r = t - l * (HIDDEN * HIDDEN);
    int k = r / HIDDEN, n = r - k * HIDDEN;
    wt1[(size_t)l * HIDDEN * HIDDEN + n * HIDDEN + k] = __float2half(w1[t]);
    wt2[(size_t)l * HIDDEN * HIDDEN + n * HIDDEN + k] = __float2half(w2[t]);
}

// ---------------------------------------------------------------------------
// GIN aggregation (R9/R10): half8 loads, 4 rows/wave-load, unroll-16,
// shfl butterfly reduce, fp32 accumulate. At random-access BW floor.
// ---------------------------------------------------------------------------
__global__ void gather_kernel(const __half* __restrict__ Xh, __half* __restrict__ Zh,
                              const int* __restrict__ row_ptr,
                              const int* __restrict__ csr_src) {
    int wave = (blockIdx.x * blockDim.x + threadIdx.x) >> 6;
    int lane = threadIdx.x & 63;
    if (wave >= N_NODES) return;
    const int grp = lane >> 4;
    const int m   = lane & 15;
    const half8* H8 = (const half8*)Xh;

    float8 acc = {0.f,0.f,0.f,0.f,0.f,0.f,0.f,0.f};
    int k = row_ptr[wave];
    const int end = row_ptr[wave + 1];

    for (; k + 16 <= end; k += 16) {
        int n0 = csr_src[k + grp];
        int n1 = csr_src[k + 4 + grp];
        int n2 = csr_src[k + 8 + grp];
        int n3 = csr_src[k + 12 + grp];
        half8 v0 = H8[(size_t)n0 * 16 + m];
        half8 v1 = H8[(size_t)n1 * 16 + m];
        half8 v2 = H8[(size_t)n2 * 16 + m];
        half8 v3 = H8[(size_t)n3 * 16 + m];
        acc += __builtin_convertvector(v0, float8);
        acc += __builtin_convertvector(v1, float8);
        acc += __builtin_convertvector(v2, float8);
        acc += __builtin_convertvector(v3, float8);
    }
    if (k + 8 <= end) {
        int n0 = csr_src[k + grp];
        int n1 = csr_src[k + 4 + grp];
        half8 v0 = H8[(size_t)n0 * 16 + m];
        half8 v1 = H8[(size_t)n1 * 16 + m];
        acc += __builtin_convertvector(v0, float8);
        acc += __builtin_convertvector(v1, float8);
        k += 8;
    }
    if (k + 4 <= end) {
        int n0 = csr_src[k + grp];
        half8 v0 = H8[(size_t)n0 * 16 + m];
        acc += __builtin_convertvector(v0, float8);
        k += 4;
    }
    int rem = end - k;
    if (grp < rem) {
        int n0 = csr_src[k + grp];
        half8 v0 = H8[(size_t)n0 * 16 + m];
        acc += __builtin_convertvector(v0, float8);
    }

#pragma unroll
    for (int j = 0; j < 8; ++j) acc[j] += __shfl_xor(acc[j], 16);
#pragma unroll
    for (int j = 0; j < 8; ++j) acc[j] += __shfl_xor(acc[j], 32);

    half8 sv = H8[(size_t)wave * 16 + m];
    acc += __builtin_convertvector(sv, float8);

    if (grp == 0) {
        half8 o = __builtin_convertvector(acc, half8);
        ((half8*)Zh)[(size_t)wave * 16 + m] = o;
    }
}

// ---------------------------------------------------------------------------
// Register-resident-W MFMA stage: C = relu(A @ W + bias), fp16 io, fp32 acc.
// Each wave preloads ALL 32 W^T B-frags (128 VGPR, L2-hot) + 8 bias scalars
// ONCE, then grid-strides over 16-row tiles. Inside the loop: 4 A-frag loads
// + 32 MFMAs in 8 INDEPENDENT accumulator chains (R10 lesson: mmfused was
// latency-bound at MfmaUtil 3.5% -- serial acc chain + in-loop W reloads).
// 16 | 100000 -> no row clamp. No LDS, no barriers.
// ---------------------------------------------------------------------------
#define MM_BLOCKS 512
__global__ __launch_bounds__(256, 2) void mm_stage_kernel(const __half* __restrict__ A,
                                                          const __half* __restrict__ Wt,
                                                          const float* __restrict__ bias,
                                                          __half* __restrict__ C16) {
    const int gwave = (blockIdx.x * 256 + threadIdx.x) >> 6;
    const int lane  = threadIdx.x & 63;
    const int m = lane & 15;
    const int q = lane >> 4;
    const int nwaves = MM_BLOCKS * 4;
    const int NTILES = N_NODES / 16;   // 6250

    // preload full W^T as B-frags: wf[ct][c] covers cols ct*16+m, k = c*32 chunk
    half8 wf[8][4];
    float bl[8];
#pragma unroll
    for (int ct = 0; ct < 8; ++ct) {
        const half8* Wrow = (const half8*)(Wt + (size_t)(ct * 16 + m) * HIDDEN);
#pragma unroll
        for (int c = 0; c < 4; ++c) wf[ct][c] = Wrow[c * 4 + q];
        bl[ct] = bias[ct * 16 + m];
    }

    for (int t = gwave; t < NTILES; t += nwaves) {
        const half8* Arow = (const half8*)(A + (size_t)(t * 16 + m) * HIDDEN);
        half8 a0 = Arow[q];
        half8 a1 = Arow[4 + q];
        half8 a2 = Arow[8 + q];
        half8 a3 = Arow[12 + q];
#pragma unroll
        for (int ct = 0; ct < 8; ++ct) {
            floatx4 acc = {0.f, 0.f, 0.f, 0.f};
            acc = __builtin_amdgcn_mfma_f32_16x16x32_f16(a0, wf[ct][0], acc, 0, 0, 0);
            acc = __builtin_amdgcn_mfma_f32_16x16x32_f16(a1, wf[ct][1], acc, 0, 0, 0);
            acc = __builtin_amdgcn_mfma_f32_16x16x32_f16(a2, wf[ct][2], acc, 0, 0, 0);
            acc = __builtin_amdgcn_mfma_f32_16x16x32_f16(a3, wf[ct][3], acc, 0, 0, 0);
            const int n = ct * 16 + m;
#pragma unroll
            for (int r = 0; r < 4; ++r) {
                int row = t * 16 + q * 4 + r;
                float v = fmaxf(acc[r] + bl[ct], 0.f);
                C16[(size_t)row * HIDDEN + n] = __float2half(v);
            }
        }
    }
}

// ---------------------------------------------------------------------------
#define POOL_CHUNK 128
__global__ void pool_kernel(const __half* __restrict__ Xh, const int* __restrict__ batch,
                            float* __restrict__ pooled, int layer) {
    const int f = threadIdx.x;
    int start = blockIdx.x * POOL_CHUNK;
    int end = start + POOL_CHUNK;
    if (end > N_NODES) end = N_NODES;
    float acc = 0.f;
    int gcur = batch[start];
    for (int n = start; n < end; ++n) {
        int g = batch[n];
        if (g != gcur) {
            atomicAdd(&pooled[(size_t)gcur * (HIDDEN * N_LAYERS) + layer * HIDDEN + f], acc);
            acc = 0.f;
            gcur = g;
        }
        acc += __half2float(Xh[(size_t)n * HIDDEN + f]);
    }
    atomicAdd(&pooled[(size_t)gcur * (HIDDEN * N_LAYERS) + layer * HIDDEN + f], acc);
}

// ---------------------------------------------------------------------------
__global__ __launch_bounds__(128) void cls_kernel(const float* __restrict__ pooled,
                                                  const float* __restrict__ w1,
                                                  const float* __restrict__ b1,
                                                  const float* __restrict__ w2,
                                                  const float* __restrict__ b2,
                                                  const float* __restrict__ w3,
                                                  const float* __restrict__ b3,
                                                  float* __restrict__ out) {
    __shared__ float hin[HIDDEN * N_LAYERS];
    __shared__ float h1[HIDDEN];
    __shared__ float red[HIDDEN];
    const int g = blockIdx.x;
    const int t = threadIdx.x;

    for (int i = t; i < HIDDEN * N_LAYERS; i += 128)
        hin[i] = pooled[(size_t)g * (HIDDEN * N_LAYERS) + i];
    __syncthreads();

    float s = 0.f;
    for (int k = 0; k < HIDDEN * N_LAYERS; ++k) s += hin[k] * w1[(size_t)k * HIDDEN + t];
    s = fmaxf(s + b1[t], 0.f);
    h1[t] = s;
    __syncthreads();

    float s2 = 0.f;
    for (int k = 0; k < HIDDEN; ++k) s2 += h1[k] * w2[(size_t)k * HIDDEN + t];
    s2 = fmaxf(s2 + b2[t], 0.f);

    red[t] = s2 * w3[t];
    __syncthreads();
    for (int off = 64; off > 0; off >>= 1) {
        if (t < off) red[t] += red[t + off];
        __syncthreads();
    }
    if (t == 0) out[g] = red[0] + b3[0];
}

// ---------------------------------------------------------------------------
extern "C" void kernel_launch(void* const* d_in, const int* in_sizes, int n_in,
                              void* d_out, int out_size, void* d_ws, size_t ws_size,
                              hipStream_t stream) {
    const float* X     = (const float*)d_in[0];
    const int*   ei    = (const int*)d_in[1];
    const int*   batch = (const int*)d_in[2];
    const float* w1all = (const float*)d_in[3];
    const float* b1all = (const float*)d_in[4];
    const float* w2all = (const float*)d_in[5];
    const float* b2all = (const float*)d_in[6];
    const float* cw1   = (const float*)d_in[7];
    const float* cb1   = (const float*)d_in[8];
    const float* cw2   = (const float*)d_in[9];
    const float* cb2   = (const float*)d_in[10];
    const float* cw3   = (const float*)d_in[11];
    const float* cb3   = (const float*)d_in[12];
    float* out = (float*)d_out;

    const int* src = ei;
    const int* dst = ei + N_EDGES;

    char* p = (char*)d_ws;
    auto alloc = [&](size_t bytes) {
        char* r = p;
        p += (bytes + 255) & ~(size_t)255;
        return r;
    };
    __half* hA      = (__half*)alloc((size_t)N_NODES * HIDDEN * sizeof(__half));
    __half* hB      = (__half*)alloc((size_t)N_NODES * HIDDEN * sizeof(__half));
    __half* zh      = (__half*)alloc((size_t)N_NODES * HIDDEN * sizeof(__half));
    __half* m1h     = (__half*)alloc((size_t)N_NODES * HIDDEN * sizeof(__half));
    __half* wt1     = (__half*)alloc((size_t)N_LAYERS * HIDDEN * HIDDEN * sizeof(__half));
    __half* wt2     = (__half*)alloc((size_t)N_LAYERS * HIDDEN * HIDDEN * sizeof(__half));
    int2*   wedge   = (int2*)alloc((size_t)N_EDGES * sizeof(int2));
    int*    csr     = (int*)alloc((size_t)N_EDGES * sizeof(int));
    int*    rowp    = (int*)alloc((size_t)(N_NODES + 1) * sizeof(int));
    int*    counts  = (int*)alloc((size_t)BIN_BLOCKS * N_WIN * sizeof(int));
    int*    offsets = (int*)alloc((size_t)BIN_BLOCKS * N_WIN * sizeof(int));
    int*    colsum  = (int*)alloc((size_t)N_WIN * sizeof(int));
    int*    winbase = (int*)alloc((size_t)(N_WIN + 1) * sizeof(int));
    float*  pooled  = (float*)alloc((size_t)N_GRAPHS * HIDDEN * N_LAYERS * sizeof(float));

    hipMemsetAsync(pooled, 0, (size_t)N_GRAPHS * HIDDEN * N_LAYERS * sizeof(float), stream);

    // CSR build: 400-way counting sort + fused per-window csr
    win_count_kernel<<<BIN_BLOCKS, 256, 0, stream>>>(dst, counts);
    win_scan1_kernel<<<N_WIN, 512, 0, stream>>>(counts, offsets, colsum);
    win_scan2_kernel<<<1, 512, 0, stream>>>(colsum, winbase);
    win_place_kernel<<<BIN_BLOCKS, 256, 0, stream>>>(src, dst, offsets, winbase, wedge);
    win_csr_kernel<<<N_WIN, 256, 0, stream>>>(wedge, winbase, rowp, csr);

    const int f2h_grid = ((N_NODES * HIDDEN / 8) + 255) / 256;
    f2h_kernel<<<f2h_grid, 256, 0, stream>>>(X, hA);
    wconv_kernel<<<(N_LAYERS * HIDDEN * HIDDEN + 255) / 256, 256, 0, stream>>>(w1all, w2all, wt1, wt2);

    const int gat_grid  = (N_NODES + 3) / 4;
    const int pool_grid = (N_NODES + POOL_CHUNK - 1) / POOL_CHUNK;

    __half* hcur = hA;
    for (int l = 0; l < N_LAYERS; ++l) {
        __half* hnext = (l & 1) ? hA : hB;
        gather_kernel<<<gat_grid, 256, 0, stream>>>(hcur, zh, rowp, csr);
        mm_stage_kernel<<<MM_BLOCKS, 256, 0, stream>>>(zh,
                                                       wt1 + (size_t)l * HIDDEN * HIDDEN,
                                                       b1all + (size_t)l * HIDDEN,
                                                       m1h);
        mm_stage_kernel<<<MM_BLOCKS, 256, 0, stream>>>(m1h,
                                                       wt2 + (size_t)l * HIDDEN * HIDDEN,
                                                       b2all + (size_t)l * HIDDEN,
                                                       hnext);
        pool_kernel<<<pool_grid, POOL_CHUNK, 0, stream>>>(hnext, batch, pooled, l);
        hcur = hnext;
    }

    cls_kernel<<<N_GRAPHS, 128, 0, stream>>>(pooled, cw1, cb1, cw2, cb2, cw3, cb3, out);
}